// Round 3
// baseline (467.060 us; speedup 1.0000x reference)
//
#include <hip/hip_runtime.h>
#include <hip/hip_bf16.h>

#define B_ 16
#define N_ 2048
#define D_ 64
#define KCS 264   // per-wave K slab chunk stride (bf16): 32 rows*8 + 8 pad (bank-spread)
#define VTS 36    // per-wave V^T row stride (bf16): 32 + 4 (with k-XOR swizzle)

typedef __bf16 bf16x8 __attribute__((ext_vector_type(8)));
typedef __bf16 bf16x4 __attribute__((ext_vector_type(4)));
typedef float  f32x4  __attribute__((ext_vector_type(4)));
typedef float  f32x16 __attribute__((ext_vector_type(16)));

// load 8 bf16 from an 8B-aligned LDS address (two b64 reads)
static __device__ __forceinline__ bf16x8 ld_frag(const __bf16* p) {
  bf16x4 lo = *(const bf16x4*)p;
  bf16x4 hi = *(const bf16x4*)(p + 4);
  return __builtin_shufflevector(lo, hi, 0, 1, 2, 3, 4, 5, 6, 7);
}

// coalesced 8x dwordx4 load of a 32-row x 64-col f32 tile region (2048 floats):
// lane gets rows 4j+(lane>>4), cols (lane&15)*4 .. +3   (1 KB contiguous / instr)
static __device__ __forceinline__ void loadT(const float* base, int lane, f32x4* r) {
#pragma unroll
  for (int j = 0; j < 8; ++j)
    r[j] = *(const f32x4*)(base + j * 256 + lane * 4);
}

// stage loaded K tile into per-wave frag slab: Kp[c*KCS + n*8 + t] = K[n][8c+t]
// b64 writes land on all 32 banks (KCS=264 => chunk stride 528B ≡ 16 mod 128)
static __device__ __forceinline__ void stageKw(__bf16* Kp, int lane, const f32x4* r) {
  __bf16* dst = &Kp[((lane & 15) >> 1) * KCS + (lane >> 4) * 8 + (lane & 1) * 4];
#pragma unroll
  for (int j = 0; j < 8; ++j) {
    bf16x4 w;
#pragma unroll
    for (int i = 0; i < 4; ++i) w[i] = (__bf16)r[j][i];
    *(bf16x4*)&dst[j * 32] = w;   // row 4j+r0 => +32 bf16 per j
  }
}

// stage loaded V tile transposed into per-wave V^T slab with k-XOR swizzle:
// Vt[d*VTS + (k ^ ((d>>4)&3)<<3)] = V[k][d]  -- b16 writes conflict-free
static __device__ __forceinline__ void stageVw(__bf16* Vt, int lane, const f32x4* r) {
  const int d0 = (lane & 15) * 4;
  const int r0 = lane >> 4;
  const int sw = ((lane & 15) >> 2) << 3;   // == ((d>>4)&3)<<3 for d0..d0+3
#pragma unroll
  for (int j = 0; j < 8; ++j) {
    const int k = (4 * j + r0) ^ sw;
#pragma unroll
    for (int i = 0; i < 4; ++i)
      Vt[(d0 + i) * VTS + k] = (__bf16)r[j][i];
  }
}

__global__ __launch_bounds__(256, 2)
void General_Attention_62251255988379_kernel(const float* __restrict__ Q,
                                             const float* __restrict__ K,
                                             const float* __restrict__ V,
                                             float* __restrict__ out) {
  __shared__ __bf16 QsL[4096];               // shared Q tile (staged once)
  __shared__ __bf16 KpL[4 * 8 * KCS];        // per-wave K frag slab (single-buf)
  __shared__ __bf16 VtL[2][4 * 64 * VTS];    // per-wave V^T slab (double-buf)
  __shared__ __bf16 PtW[4 * 32 * 36];        // per-wave P slab
  __shared__ float  lsum[64];

  const int tid  = threadIdx.x;
  const int blk  = blockIdx.x;
  const int bb   = blk & 15;
  const int u    = blk >> 4;                       // heavy tiles dispatch first;
  const int rb   = (u < 16) ? (31 - u) : (u - 16); // CU pair (c,c+256) = const work
  const int row0 = rb * 64;
  const int lane = tid & 63;
  const int wave = tid >> 6;
  const int wr   = wave & 1;
  const int wc   = wave >> 1;
  const int ln   = lane & 31;
  const int half = lane >> 5;

  const float* Qb = Q + (size_t)bb * N_ * D_;
  const float* Kb = K + (size_t)bb * N_ * D_;
  const float* Vb = V + (size_t)bb * N_ * D_;
  float* Ob = out + (size_t)bb * N_ * D_;
  float* Ab = out + (size_t)B_ * N_ * D_ + (size_t)bb * N_ * N_;

  if (tid < 64) lsum[tid] = 0.0f;

  // ---- stage Q tile once (shared), pre-scaled by 1/sqrt(D)=0.125 ----
  {
    const int m   = tid >> 2;
    const int c4q = tid & 3;
    const f32x4* src = (const f32x4*)(Qb + (size_t)(row0 + m) * D_ + c4q * 16);
    f32x4 f0 = src[0], f1 = src[1], f2 = src[2], f3 = src[3];
    bf16x8 w0, w1;
#pragma unroll
    for (int i = 0; i < 4; ++i) {
      w0[i]     = (__bf16)(f0[i] * 0.125f);
      w0[i + 4] = (__bf16)(f1[i] * 0.125f);
      w1[i]     = (__bf16)(f2[i] * 0.125f);
      w1[i + 4] = (__bf16)(f3[i] * 0.125f);
    }
    *(bf16x8*)&QsL[(2 * c4q + 0) * 512 + m * 8] = w0;
    *(bf16x8*)&QsL[(2 * c4q + 1) * 512 + m * 8] = w1;
  }
  __syncthreads();

  bf16x8 qf[4];
#pragma unroll
  for (int kk = 0; kk < 4; ++kk)
    qf[kk] = *(const bf16x8*)&QsL[(2 * kk + half) * 512 + (32 * wr + ln) * 8];

  const int nt = rb + 1;
  __bf16* Kp = &KpL[wave * 8 * KCS];
  const float* KtB = Kb + (size_t)(32 * wc) * D_;   // wave's 32 k-rows
  const float* VtB = Vb + (size_t)(32 * wc) * D_;

  // ===================== pass A: row sums of exp(s) — BARRIER-FREE ==========
  f32x4 kraw[8];
  loadT(KtB, lane, kraw);                 // tile 0
  stageKw(Kp, lane, kraw);
  if (nt > 1) loadT(KtB + (size_t)64 * D_, lane, kraw);   // tile 1

  float sums[16];
#pragma unroll
  for (int r = 0; r < 16; ++r) sums[r] = 0.0f;

#pragma unroll 1
  for (int i = 0; i < nt; ++i) {
    bf16x8 kf[4];
#pragma unroll
    for (int kk = 0; kk < 4; ++kk)        // reads of tile i (in-order DS: safe
      kf[kk] = *(const bf16x8*)&Kp[(2 * kk + half) * KCS + ln * 8];
    if (i + 1 < nt) stageKw(Kp, lane, kraw);                      // stage i+1
    if (i + 2 < nt) loadT(KtB + (size_t)(i + 2) * 64 * D_, lane, kraw);
    f32x16 s;
#pragma unroll
    for (int j = 0; j < 16; ++j) s[j] = 0.0f;
#pragma unroll
    for (int kk = 0; kk < 4; ++kk)
      s = __builtin_amdgcn_mfma_f32_32x32x16_bf16(qf[kk], kf[kk], s, 0, 0, 0);
    const bool diag = (i == rb);
#pragma unroll
    for (int r = 0; r < 16; ++r) {
      float e = __expf(s[r]);
      if (diag) {
        const int ro = (r & 3) + 8 * (r >> 2) + 4 * half;
        e = ((32 * wc + ln) <= (32 * wr + ro)) ? e : 0.0f;
      }
      sums[r] += e;
    }
  }

  // butterfly-reduce across the 32 lanes holding each row's columns
#pragma unroll
  for (int r = 0; r < 16; ++r) {
    float v = sums[r];
    v += __shfl_xor(v, 1);
    v += __shfl_xor(v, 2);
    v += __shfl_xor(v, 4);
    v += __shfl_xor(v, 8);
    v += __shfl_xor(v, 16);
    sums[r] = v;
  }
  if (ln == 0) {
#pragma unroll
    for (int r = 0; r < 16; ++r) {
      const int ro = (r & 3) + 8 * (r >> 2) + 4 * half;
      atomicAdd(&lsum[32 * wr + ro], sums[r]);
    }
  }
  __syncthreads();

  float linv[16];
#pragma unroll
  for (int r = 0; r < 16; ++r) {
    const int ro = (r & 3) + 8 * (r >> 2) + 4 * half;
    linv[r] = 1.0f / lsum[32 * wr + ro];
  }

  // ===================== pass B: att writes + O = P.V — BARRIER-FREE ========
  f32x4 vraw[8];
  loadT(KtB, lane, kraw);
  loadT(VtB, lane, vraw);
  stageKw(Kp, lane, kraw);
  stageVw(&VtL[0][wave * 64 * VTS], lane, vraw);
  if (nt > 1) {
    loadT(KtB + (size_t)64 * D_, lane, kraw);
    loadT(VtB + (size_t)64 * D_, lane, vraw);
  }

  f32x16 o0, o1;
#pragma unroll
  for (int i = 0; i < 16; ++i) { o0[i] = 0.0f; o1[i] = 0.0f; }
  __bf16* Pt = &PtW[wave * 32 * 36];
  const int sw0 = ((ln >> 4) & 1) << 3;   // V^T read swizzle for d=ln (b1: ^16)

#pragma unroll 1
  for (int i = 0; i < nt; ++i) {
    bf16x8 kf[4];
#pragma unroll
    for (int kk = 0; kk < 4; ++kk)
      kf[kk] = *(const bf16x8*)&Kp[(2 * kk + half) * KCS + ln * 8];
    if (i + 1 < nt) {
      stageKw(Kp, lane, kraw);
      stageVw(&VtL[(i + 1) & 1][wave * 64 * VTS], lane, vraw);
    }
    if (i + 2 < nt) {
      loadT(KtB + (size_t)(i + 2) * 64 * D_, lane, kraw);
      loadT(VtB + (size_t)(i + 2) * 64 * D_, lane, vraw);
    }
    f32x16 s;
#pragma unroll
    for (int j = 0; j < 16; ++j) s[j] = 0.0f;
#pragma unroll
    for (int kk = 0; kk < 4; ++kk)
      s = __builtin_amdgcn_mfma_f32_32x32x16_bf16(qf[kk], kf[kk], s, 0, 0, 0);
    const bool diag = (i == rb);
    const int  c0   = i * 64;
#pragma unroll
    for (int r = 0; r < 16; ++r) {
      const int ro = (r & 3) + 8 * (r >> 2) + 4 * half;
      float e = __expf(s[r]);
      if (diag) e = ((32 * wc + ln) <= (32 * wr + ro)) ? e : 0.0f;
      const float pv = e * linv[r];
      __builtin_nontemporal_store(pv,
          Ab + (size_t)(row0 + 32 * wr + ro) * N_ + c0 + 32 * wc + ln);
      Pt[ro * 36 + ln] = (__bf16)pv;   // wave-private slab
    }
    const __bf16* Vtc = &VtL[i & 1][wave * 64 * VTS];
#pragma unroll
    for (int kk2 = 0; kk2 < 2; ++kk2) {
      const int koff = 16 * kk2 + 8 * half;
      bf16x8 af = ld_frag(&Pt[ln * 36 + koff]);
      bf16x8 b0 = ld_frag(&Vtc[ln * VTS + (koff ^ sw0)]);
      bf16x8 b1 = ld_frag(&Vtc[(32 + ln) * VTS + (koff ^ sw0 ^ 16)]);
      o0 = __builtin_amdgcn_mfma_f32_32x32x16_bf16(af, b0, o0, 0, 0, 0);
      o1 = __builtin_amdgcn_mfma_f32_32x32x16_bf16(af, b1, o1, 0, 0, 0);
    }
  }

  // ---- cross-wave O reduction (wc=1 partials -> wc=0) and store ----
  __syncthreads();                     // KpL must be dead in ALL waves first
  float* Ored = (float*)&KpL[0];       // 16.5 KB scratch, reuse K slabs
  if (wc == 1) {
#pragma unroll
    for (int r = 0; r < 16; ++r) {
      const int ro = (r & 3) + 8 * (r >> 2) + 4 * half;
      Ored[(32 * wr + ro) * 64 + ln]      = o0[r];
      Ored[(32 * wr + ro) * 64 + 32 + ln] = o1[r];
    }
  }
  __syncthreads();
  if (wc == 0) {
#pragma unroll
    for (int r = 0; r < 16; ++r) {
      const int ro = (r & 3) + 8 * (r >> 2) + 4 * half;
      float* op = Ob + (size_t)(row0 + 32 * wr + ro) * D_;
      __builtin_nontemporal_store(o0[r] + Ored[(32 * wr + ro) * 64 + ln], op + ln);
      __builtin_nontemporal_store(o1[r] + Ored[(32 * wr + ro) * 64 + 32 + ln], op + 32 + ln);
    }
  }

  // ---- zero-fill strictly-upper columns of att for this row tile ----
  const int cz0 = 64 * (rb + 1);
  if (cz0 < N_) {
    f32x4 z = {0.0f, 0.0f, 0.0f, 0.0f};
#pragma unroll 1
    for (int rr = (tid >> 6); rr < 64; rr += 4) {
      float* rowp = Ab + (size_t)(row0 + rr) * N_;
      for (int x = cz0 + (tid & 63) * 4; x < N_; x += 256)
        __builtin_nontemporal_store(z, (f32x4*)(rowp + x));
    }
  }
}

extern "C" void kernel_launch(void* const* d_in, const int* in_sizes, int n_in,
                              void* d_out, int out_size, void* d_ws, size_t ws_size,
                              hipStream_t stream) {
  const float* Q = (const float*)d_in[0];
  const float* K = (const float*)d_in[1];
  const float* V = (const float*)d_in[2];
  (void)in_sizes; (void)n_in; (void)out_size; (void)d_ws; (void)ws_size;
  float* out = (float*)d_out;
  General_Attention_62251255988379_kernel<<<dim3(512), dim3(256), 0, stream>>>(Q, K, V, out);
}

// Round 4
// 456.376 us; speedup vs baseline: 1.0234x; 1.0234x over previous
//
#include <hip/hip_runtime.h>
#include <hip/hip_bf16.h>

#define B_ 16
#define N_ 2048
#define D_ 64

typedef __bf16 bf16x8 __attribute__((ext_vector_type(8)));
typedef __bf16 bf16x4 __attribute__((ext_vector_type(4)));
typedef __bf16 bf16x2 __attribute__((ext_vector_type(2)));
typedef float  f32x4  __attribute__((ext_vector_type(4)));
typedef float  f32x16 __attribute__((ext_vector_type(16)));

// load 8 bf16 from an 8B-aligned LDS address (two b64 reads)
static __device__ __forceinline__ bf16x8 ld_frag(const __bf16* p) {
  bf16x4 lo = *(const bf16x4*)p;
  bf16x4 hi = *(const bf16x4*)(p + 4);
  return __builtin_shufflevector(lo, hi, 0, 1, 2, 3, 4, 5, 6, 7);
}

// convert 16 staged floats -> bf16 frag layout [kchunk][row][8]
static __device__ __forceinline__ void stage_K(__bf16* dst, int n, int c4,
                                               const f32x4* f) {
  bf16x8 w0, w1;
#pragma unroll
  for (int i = 0; i < 4; ++i) {
    w0[i] = (__bf16)f[0][i]; w0[i + 4] = (__bf16)f[1][i];
    w1[i] = (__bf16)f[2][i]; w1[i + 4] = (__bf16)f[3][i];
  }
  *(bf16x8*)&dst[(2 * c4 + 0) * 512 + n * 8] = w0;
  *(bf16x8*)&dst[(2 * c4 + 1) * 512 + n * 8] = w1;
}

// V^T staging: v[0],v[1] = rows 2g,2g+1 ; v[2],v[3] = rows 2g+32,2g+33
static __device__ __forceinline__ void stage_V(__bf16* dst, int g, int n0,
                                               const f32x4* v) {
#pragma unroll
  for (int p = 0; p < 2; ++p) {
    const int k = 2 * g + 32 * p;
#pragma unroll
    for (int i = 0; i < 4; ++i) {
      bf16x2 pr;
      pr[0] = (__bf16)v[2 * p][i];
      pr[1] = (__bf16)v[2 * p + 1][i];
      *(bf16x2*)&dst[(n0 + i) * 68 + k] = pr;
    }
  }
}

__global__ __launch_bounds__(256, 2)
void General_Attention_62251255988379_kernel(const float* __restrict__ Q,
                                             const float* __restrict__ K,
                                             const float* __restrict__ V,
                                             float* __restrict__ out) {
  __shared__ __bf16 QsL[4096];
  __shared__ __bf16 KsL[2][4096];       // double-buffered K tile (frag layout)
  __shared__ __bf16 VtL[2][4352];       // double-buffered V^T [d][k], stride 68
  __shared__ __bf16 PtW[4 * 32 * 36];   // per-wave P slab [32 rows][36], stride 36
  __shared__ float  lsum[64];

  const int tid  = threadIdx.x;
  const int blk  = blockIdx.x;
  const int bb   = blk & 15;
  const int u    = blk >> 4;                       // heavy tiles dispatch first;
  const int rb   = (u < 16) ? (31 - u) : (u - 16); // CU pair (c,c+256) = const work
  const int row0 = rb * 64;
  const int lane = tid & 63;
  const int wave = tid >> 6;
  const int wr   = wave & 1;
  const int wc   = wave >> 1;
  const int ln   = lane & 31;
  const int half = lane >> 5;

  const float* Qb = Q + (size_t)bb * N_ * D_;
  const float* Kb = K + (size_t)bb * N_ * D_;
  const float* Vb = V + (size_t)bb * N_ * D_;
  float* Ob = out + (size_t)bb * N_ * D_;
  float* Ab = out + (size_t)B_ * N_ * D_ + (size_t)bb * N_ * N_;

  if (tid < 64) lsum[tid] = 0.0f;

  // ---- stage Q tile once, pre-scaled by 1/sqrt(D)=0.125 ----
  {
    const int m  = tid >> 2;
    const int c4 = tid & 3;
    const f32x4* src = (const f32x4*)(Qb + (size_t)(row0 + m) * D_ + c4 * 16);
    f32x4 f0 = src[0], f1 = src[1], f2 = src[2], f3 = src[3];
    bf16x8 w0, w1;
#pragma unroll
    for (int i = 0; i < 4; ++i) {
      w0[i]     = (__bf16)(f0[i] * 0.125f);
      w0[i + 4] = (__bf16)(f1[i] * 0.125f);
      w1[i]     = (__bf16)(f2[i] * 0.125f);
      w1[i + 4] = (__bf16)(f3[i] * 0.125f);
    }
    *(bf16x8*)&QsL[(2 * c4 + 0) * 512 + m * 8] = w0;
    *(bf16x8*)&QsL[(2 * c4 + 1) * 512 + m * 8] = w1;
  }
  __syncthreads();

  bf16x8 qf[4];
#pragma unroll
  for (int kk = 0; kk < 4; ++kk)
    qf[kk] = *(const bf16x8*)&QsL[(2 * kk + half) * 512 + (32 * wr + ln) * 8];

  const int n_st = tid >> 2;
  const int c4   = tid & 3;
  const float* Kst = Kb + (size_t)n_st * D_ + c4 * 16;

  // ===================== pass A: row sums of exp(s) =====================
  f32x4 kp[4];
  {
    const f32x4* kq = (const f32x4*)Kst;
    kp[0] = kq[0]; kp[1] = kq[1]; kp[2] = kq[2]; kp[3] = kq[3];
  }
  stage_K(KsL[0], n_st, c4, kp);

  float sums[16];
#pragma unroll
  for (int r = 0; r < 16; ++r) sums[r] = 0.0f;
  __syncthreads();

#pragma unroll 1
  for (int ct = 0; ct <= rb; ++ct) {
    const int cur = ct & 1;
    if (ct < rb) {  // prefetch next K tile into regs (overlaps compute)
      const f32x4* kq = (const f32x4*)(Kst + (size_t)(ct + 1) * 64 * D_);
      kp[0] = kq[0]; kp[1] = kq[1]; kp[2] = kq[2]; kp[3] = kq[3];
    }
    f32x16 s;
#pragma unroll
    for (int i = 0; i < 16; ++i) s[i] = 0.0f;
    __builtin_amdgcn_s_setprio(1);
#pragma unroll
    for (int kk = 0; kk < 4; ++kk) {
      bf16x8 kf = *(const bf16x8*)&KsL[cur][(2 * kk + half) * 512 + (32 * wc + ln) * 8];
      s = __builtin_amdgcn_mfma_f32_32x32x16_bf16(qf[kk], kf, s, 0, 0, 0);
    }
    __builtin_amdgcn_s_setprio(0);
    const bool diag = (ct == rb);
#pragma unroll
    for (int r = 0; r < 16; ++r) {
      float e = __expf(s[r]);
      if (diag) {
        const int ro = (r & 3) + 8 * (r >> 2) + 4 * half;
        e = ((32 * wc + ln) <= (32 * wr + ro)) ? e : 0.0f;
      }
      sums[r] += e;
    }
    if (ct < rb) stage_K(KsL[cur ^ 1], n_st, c4, kp);
    __syncthreads();
  }

  // butterfly-reduce across the 32 lanes holding each row's columns
#pragma unroll
  for (int r = 0; r < 16; ++r) {
    float v = sums[r];
    v += __shfl_xor(v, 1);
    v += __shfl_xor(v, 2);
    v += __shfl_xor(v, 4);
    v += __shfl_xor(v, 8);
    v += __shfl_xor(v, 16);
    sums[r] = v;
  }
  if (ln == 0) {
#pragma unroll
    for (int r = 0; r < 16; ++r) {
      const int ro = (r & 3) + 8 * (r >> 2) + 4 * half;
      atomicAdd(&lsum[32 * wr + ro], sums[r]);
    }
  }
  __syncthreads();

  float linv[16];
#pragma unroll
  for (int r = 0; r < 16; ++r) {
    const int ro = (r & 3) + 8 * (r >> 2) + 4 * half;
    linv[r] = 1.0f / lsum[32 * wr + ro];
  }

  // ===================== pass B: att writes + O = P.V =====================
  const int gV  = tid >> 4;
  const int n0v = (tid & 15) * 4;
  const float* Vst = Vb + (size_t)(2 * gV) * D_ + n0v;

  f32x4 vp[4];
  {
    const f32x4* kq = (const f32x4*)Kst;
    kp[0] = kq[0]; kp[1] = kq[1]; kp[2] = kq[2]; kp[3] = kq[3];
    vp[0] = *(const f32x4*)(Vst);
    vp[1] = *(const f32x4*)(Vst + D_);
    vp[2] = *(const f32x4*)(Vst + 32 * D_);
    vp[3] = *(const f32x4*)(Vst + 33 * D_);
  }
  stage_K(KsL[0], n_st, c4, kp);
  stage_V(VtL[0], gV, n0v, vp);

  f32x16 o0, o1;
#pragma unroll
  for (int i = 0; i < 16; ++i) { o0[i] = 0.0f; o1[i] = 0.0f; }
  __bf16* Pt = &PtW[wave * 32 * 36];
  __syncthreads();

#pragma unroll 1
  for (int ct = 0; ct <= rb; ++ct) {
    const int cur = ct & 1;
    const int c0  = ct * 64;
    if (ct < rb) {  // prefetch next K+V tiles into regs
      const size_t off = (size_t)(ct + 1) * 64 * D_;
      const f32x4* kq = (const f32x4*)(Kst + off);
      kp[0] = kq[0]; kp[1] = kq[1]; kp[2] = kq[2]; kp[3] = kq[3];
      vp[0] = *(const f32x4*)(Vst + off);
      vp[1] = *(const f32x4*)(Vst + off + D_);
      vp[2] = *(const f32x4*)(Vst + off + 32 * D_);
      vp[3] = *(const f32x4*)(Vst + off + 33 * D_);
    }
    // S = Q.K^T for this tile
    f32x16 s;
#pragma unroll
    for (int i = 0; i < 16; ++i) s[i] = 0.0f;
    __builtin_amdgcn_s_setprio(1);
#pragma unroll
    for (int kk = 0; kk < 4; ++kk) {
      bf16x8 kf = *(const bf16x8*)&KsL[cur][(2 * kk + half) * 512 + (32 * wc + ln) * 8];
      s = __builtin_amdgcn_mfma_f32_32x32x16_bf16(qf[kk], kf, s, 0, 0, 0);
    }
    __builtin_amdgcn_s_setprio(0);
    const bool diag = (ct == rb);
#pragma unroll
    for (int r = 0; r < 16; ++r) {
      const int ro = (r & 3) + 8 * (r >> 2) + 4 * half;
      float e = __expf(s[r]);
      if (diag) e = ((32 * wc + ln) <= (32 * wr + ro)) ? e : 0.0f;
      const float pv = e * linv[r];
      __builtin_nontemporal_store(pv,
          Ab + (size_t)(row0 + 32 * wr + ro) * N_ + c0 + 32 * wc + ln);
      Pt[ro * 36 + ln] = (__bf16)pv;   // wave-private: no barrier needed
    }
    // O partial: this wave's 32 columns only (k-range 32), cross-wave reduce later
    __builtin_amdgcn_s_setprio(1);
#pragma unroll
    for (int kk2 = 0; kk2 < 2; ++kk2) {
      bf16x8 af = ld_frag(&Pt[ln * 36 + 16 * kk2 + 8 * half]);
      bf16x8 b0 = ld_frag(&VtL[cur][ln * 68 + 32 * wc + 16 * kk2 + 8 * half]);
      bf16x8 b1 = ld_frag(&VtL[cur][(32 + ln) * 68 + 32 * wc + 16 * kk2 + 8 * half]);
      o0 = __builtin_amdgcn_mfma_f32_32x32x16_bf16(af, b0, o0, 0, 0, 0);
      o1 = __builtin_amdgcn_mfma_f32_32x32x16_bf16(af, b1, o1, 0, 0, 0);
    }
    __builtin_amdgcn_s_setprio(0);
    if (ct < rb) {
      stage_K(KsL[cur ^ 1], n_st, c4, kp);
      stage_V(VtL[cur ^ 1], gV, n0v, vp);
    }
    __syncthreads();
  }

  // ---- cross-wave O reduction (wc=1 partials -> wc=0) and store ----
  float* Ored = (float*)&KsL[0][0];  // 16 KB scratch, KsL dead now
  if (wc == 1) {
#pragma unroll
    for (int r = 0; r < 16; ++r) {
      const int ro = (r & 3) + 8 * (r >> 2) + 4 * half;
      Ored[(32 * wr + ro) * 64 + ln]      = o0[r];
      Ored[(32 * wr + ro) * 64 + 32 + ln] = o1[r];
    }
  }
  __syncthreads();
  if (wc == 0) {
#pragma unroll
    for (int r = 0; r < 16; ++r) {
      const int ro = (r & 3) + 8 * (r >> 2) + 4 * half;
      float* op = Ob + (size_t)(row0 + 32 * wr + ro) * D_;
      __builtin_nontemporal_store(o0[r] + Ored[(32 * wr + ro) * 64 + ln], op + ln);
      __builtin_nontemporal_store(o1[r] + Ored[(32 * wr + ro) * 64 + 32 + ln], op + 32 + ln);
    }
  }

  // ---- zero-fill strictly-upper columns of att for this row tile ----
  const int cz0 = 64 * (rb + 1);
  if (cz0 < N_) {
    f32x4 z = {0.0f, 0.0f, 0.0f, 0.0f};
#pragma unroll 1
    for (int rr = (tid >> 6); rr < 64; rr += 4) {
      float* rowp = Ab + (size_t)(row0 + rr) * N_;
      for (int x = cz0 + (tid & 63) * 4; x < N_; x += 256)
        __builtin_nontemporal_store(z, (f32x4*)(rowp + x));
    }
  }
}

extern "C" void kernel_launch(void* const* d_in, const int* in_sizes, int n_in,
                              void* d_out, int out_size, void* d_ws, size_t ws_size,
                              hipStream_t stream) {
  const float* Q = (const float*)d_in[0];
  const float* K = (const float*)d_in[1];
  const float* V = (const float*)d_in[2];
  (void)in_sizes; (void)n_in; (void)out_size; (void)d_ws; (void)ws_size;
  float* out = (float*)d_out;
  General_Attention_62251255988379_kernel<<<dim3(512), dim3(256), 0, stream>>>(Q, K, V, out);
}